// Round 1
// baseline (356.549 us; speedup 1.0000x reference)
//
#include <hip/hip_runtime.h>

// Problem constants (B,C,H,W) = (4,16,320,640), fp32.
constexpr int Bn = 4;
constexpr int Cn = 16;
constexpr int Hn = 320;
constexpr int Wn = 640;
constexpr int NCOL = Bn * Cn * Wn;   // 40960 vertical columns
constexpr int NROW = Bn * Cn * Hn;   // 20480 horizontal rows

// ---------------------------------------------------------------------------
// Vertical propagation. Blocks [0,160) do the forward (down) scan writing
// r_down into `outDown`; blocks [160,320) do the backward (up) scan writing
// r_up into `outUp`. Consecutive threads -> consecutive w -> fully coalesced.
// Recurrence: y = x*(1-g) + g*y_prev  ==  fma(g, y_prev - x, x).
// ---------------------------------------------------------------------------
__global__ __launch_bounds__(256) void vert_split(
    const float* __restrict__ x, const float* __restrict__ g0,
    const float* __restrict__ g1, float* __restrict__ outDown,
    float* __restrict__ outUp) {
  int tid = blockIdx.x * 256 + threadIdx.x;
  bool bwd = tid >= NCOL;
  int col = bwd ? tid - NCOL : tid;
  int w = col % Wn;
  int bc = col / Wn;
  size_t base = (size_t)bc * Hn * Wn + w;

  if (!bwd) {
    const float* xp = x + base;
    const float* gp = g0 + base;
    float* op = outDown + base;
    float y = xp[0];
    op[0] = y;
#pragma unroll 4
    for (int h = 1; h < Hn; ++h) {
      float xv = xp[(size_t)h * Wn];
      float gv = gp[(size_t)h * Wn];
      y = fmaf(gv, y - xv, xv);
      op[(size_t)h * Wn] = y;
    }
  } else {
    const float* xp = x + base;
    const float* gp = g1 + base;
    float* op = outUp + base;
    float y = xp[(size_t)(Hn - 1) * Wn];
    op[(size_t)(Hn - 1) * Wn] = y;
#pragma unroll 4
    for (int h = Hn - 2; h >= 0; --h) {
      float xv = xp[(size_t)h * Wn];
      float gv = gp[(size_t)h * Wn];
      y = fmaf(gv, y - xv, xv);
      op[(size_t)h * Wn] = y;
    }
  }
}

// Fallback (if workspace too small): each thread does fwd scan writing r_down
// to out, then bwd scan with read-max-write on out.
__global__ __launch_bounds__(256) void vert_fused(
    const float* __restrict__ x, const float* __restrict__ g0,
    const float* __restrict__ g1, float* __restrict__ out) {
  int col = blockIdx.x * 256 + threadIdx.x;
  int w = col % Wn;
  int bc = col / Wn;
  size_t base = (size_t)bc * Hn * Wn + w;
  const float* xp = x + base;
  float* op = out + base;
  {
    const float* gp = g0 + base;
    float y = xp[0];
    op[0] = y;
#pragma unroll 4
    for (int h = 1; h < Hn; ++h) {
      float xv = xp[(size_t)h * Wn];
      float gv = gp[(size_t)h * Wn];
      y = fmaf(gv, y - xv, xv);
      op[(size_t)h * Wn] = y;
    }
  }
  {
    const float* gp = g1 + base;
    float y = xp[(size_t)(Hn - 1) * Wn];
    op[(size_t)(Hn - 1) * Wn] = fmaxf(op[(size_t)(Hn - 1) * Wn], y);
#pragma unroll 4
    for (int h = Hn - 2; h >= 0; --h) {
      float xv = xp[(size_t)h * Wn];
      float gv = gp[(size_t)h * Wn];
      y = fmaf(gv, y - xv, xv);
      op[(size_t)h * Wn] = fmaxf(op[(size_t)h * Wn], y);
    }
  }
}

// ---------------------------------------------------------------------------
// Horizontal propagation: one 64-lane wave per row (4 rows per 256-thr block).
// First-order linear recurrence y_i = a_i + b_i*y_{i-1} is associative under
// (a,b) composition, so each 64-chunk is a Hillis-Steele shuffle scan with a
// scalar carry across the 10 chunks. Pass A (right) caches x + r_right in
// LDS; pass B (left) re-uses x from LDS and fuses the final 4-way max.
// ---------------------------------------------------------------------------
template <bool USE_WS>
__global__ __launch_bounds__(256) void horiz(
    const float* __restrict__ x, const float* __restrict__ g2,
    const float* __restrict__ g3, const float* __restrict__ up,
    float* __restrict__ out) {
  __shared__ float xs[4][Wn];
  __shared__ float rr[4][Wn];
  const int wave = threadIdx.x >> 6;
  const int lane = threadIdx.x & 63;
  const int row = blockIdx.x * 4 + wave;
  const size_t base = (size_t)row * Wn;
  const float* xp = x + base;
  const float* g2p = g2 + base;
  const float* g3p = g3 + base;

  // ---- pass A: r_right (forward along W) ----
  float carry = 0.0f;
#pragma unroll
  for (int c = 0; c < Wn / 64; ++c) {
    int p = c * 64 + lane;
    float xv = xp[p];
    float gv = g2p[p];
    float a = (p == 0) ? xv : xv * (1.0f - gv);
    float b = (p == 0) ? 0.0f : gv;
#pragma unroll
    for (int off = 1; off < 64; off <<= 1) {
      float a_up = __shfl_up(a, off);
      float b_up = __shfl_up(b, off);
      if (lane >= off) {
        a = fmaf(b, a_up, a);
        b = b * b_up;
      }
    }
    float y = fmaf(b, carry, a);
    carry = __shfl(y, 63);
    rr[wave][p] = y;
    xs[wave][p] = xv;
  }

  __syncthreads();

  // ---- pass B: r_left (reverse along W), fused combine + store ----
  carry = 0.0f;
#pragma unroll
  for (int c = 0; c < Wn / 64; ++c) {
    int p = c * 64 + lane;       // scan position
    int idx = (Wn - 1) - p;      // element index
    float xv = xs[wave][idx];
    float gv = g3p[idx];
    float a = (p == 0) ? xv : xv * (1.0f - gv);
    float b = (p == 0) ? 0.0f : gv;
#pragma unroll
    for (int off = 1; off < 64; off <<= 1) {
      float a_up = __shfl_up(a, off);
      float b_up = __shfl_up(b, off);
      if (lane >= off) {
        a = fmaf(b, a_up, a);
        b = b * b_up;
      }
    }
    float y = fmaf(b, carry, a);  // r_left[idx]
    carry = __shfl(y, 63);

    float v = fmaxf(rr[wave][idx], y);
    float dn = out[base + idx];
    if (USE_WS) dn = fmaxf(dn, up[base + idx]);
    out[base + idx] = fmaxf(dn, v);
  }
}

extern "C" void kernel_launch(void* const* d_in, const int* in_sizes, int n_in,
                              void* d_out, int out_size, void* d_ws,
                              size_t ws_size, hipStream_t stream) {
  const float* x = (const float*)d_in[0];
  const float* g0 = (const float*)d_in[1];
  const float* g1 = (const float*)d_in[2];
  const float* g2 = (const float*)d_in[3];
  const float* g3 = (const float*)d_in[4];
  float* out = (float*)d_out;

  size_t need = (size_t)out_size * sizeof(float);
  if (ws_size >= need) {
    float* ws = (float*)d_ws;
    // fwd half writes r_down -> out, bwd half writes r_up -> ws
    vert_split<<<(2 * NCOL) / 256, 256, 0, stream>>>(x, g0, g1, out, ws);
    horiz<true><<<NROW / 4, 256, 0, stream>>>(x, g2, g3, ws, out);
  } else {
    vert_fused<<<NCOL / 256, 256, 0, stream>>>(x, g0, g1, out);
    horiz<false><<<NROW / 4, 256, 0, stream>>>(x, g2, g3, nullptr, out);
  }
}

// Round 2
// 290.164 us; speedup vs baseline: 1.2288x; 1.2288x over previous
//
#include <hip/hip_runtime.h>

// (B,C,H,W) = (4,16,320,640), fp32 throughout.
constexpr int Bn = 4;
constexpr int Cn = 16;
constexpr int Hn = 320;
constexpr int Wn = 640;
constexpr int NCOL = Bn * Cn * Wn;   // 40960 vertical columns
constexpr int NROW = Bn * Cn * Hn;   // 20480 horizontal rows

// Vertical: segmented scan. Block = 640 threads = 10 waves; wave s owns a
// 32-row segment of 64 consecutive columns. Recurrence y = a + b*y_prev with
// a = x*(1-g), b = g (a = x, b = 0 at the sequence head). Local scan + gate
// product P live in registers; carries stitched through LDS.
constexpr int HSEG = 32;
constexpr int NSEG = Hn / HSEG;      // 10
constexpr int VBLK = NSEG * 64;      // 640 threads

__global__ __launch_bounds__(VBLK) void vert(
    const float* __restrict__ x, const float* __restrict__ g0,
    const float* __restrict__ g1, float* __restrict__ outDown,
    float* __restrict__ outUp) {
  __shared__ float As[NSEG][64], Bs[NSEG][64], Cs[NSEG][64];
  constexpr int NGRP = NCOL / 64;    // 640 column groups per direction
  int blk = blockIdx.x;
  bool bwd = blk >= NGRP;
  int grp = bwd ? blk - NGRP : blk;
  int bc = grp / (Wn / 64);
  int w0 = (grp % (Wn / 64)) * 64;
  int s = threadIdx.x >> 6;
  int l = threadIdx.x & 63;
  size_t colbase = (size_t)bc * (Hn * Wn) + w0 + l;
  const float* __restrict__ gp = bwd ? g1 : g0;
  float* __restrict__ op = bwd ? outUp : outDown;

  float y[HSEG], P[HSEG];
  float yy = 0.0f, pp = 1.0f;
#pragma unroll
  for (int i = 0; i < HSEG; ++i) {
    int r = bwd ? (Hn - 1 - (s * HSEG + i)) : (s * HSEG + i);
    size_t off = colbase + (size_t)r * Wn;
    float xv = x[off];
    float gv = gp[off];
    float b = (s == 0 && i == 0) ? 0.0f : gv;  // sequence head: y = x
    yy = fmaf(b, yy - xv, xv);                 // y = x*(1-b) + b*y_prev
    pp *= b;
    y[i] = yy;
    P[i] = pp;
  }
  As[s][l] = yy;
  Bs[s][l] = pp;
  __syncthreads();
  if (threadIdx.x < 64) {
    float c = 0.0f;
#pragma unroll
    for (int ss = 0; ss < NSEG; ++ss) {
      Cs[ss][l] = c;
      c = fmaf(Bs[ss][l], c, As[ss][l]);
    }
  }
  __syncthreads();
  float c = Cs[s][l];
#pragma unroll
  for (int i = 0; i < HSEG; ++i) {
    int r = bwd ? (Hn - 1 - (s * HSEG + i)) : (s * HSEG + i);
    op[colbase + (size_t)r * Wn] = fmaf(P[i], c, y[i]);
  }
}

// Fallback if workspace is unusable: per-thread fwd scan then bwd RMW-max.
__global__ __launch_bounds__(256) void vert_fused(
    const float* __restrict__ x, const float* __restrict__ g0,
    const float* __restrict__ g1, float* __restrict__ out) {
  int col = blockIdx.x * 256 + threadIdx.x;
  int w = col % Wn;
  int bc = col / Wn;
  size_t base = (size_t)bc * Hn * Wn + w;
  const float* xp = x + base;
  float* op = out + base;
  {
    const float* gp = g0 + base;
    float y = xp[0];
    op[0] = y;
#pragma unroll 8
    for (int h = 1; h < Hn; ++h) {
      float xv = xp[(size_t)h * Wn];
      float gv = gp[(size_t)h * Wn];
      y = fmaf(gv, y - xv, xv);
      op[(size_t)h * Wn] = y;
    }
  }
  {
    const float* gp = g1 + base;
    float y = xp[(size_t)(Hn - 1) * Wn];
    op[(size_t)(Hn - 1) * Wn] = fmaxf(op[(size_t)(Hn - 1) * Wn], y);
#pragma unroll 8
    for (int h = Hn - 2; h >= 0; --h) {
      float xv = xp[(size_t)h * Wn];
      float gv = gp[(size_t)h * Wn];
      y = fmaf(gv, y - xv, xv);
      op[(size_t)h * Wn] = fmaxf(op[(size_t)h * Wn], y);
    }
  }
}

// Horizontal: one wave per row. 40 active lanes own 16 contiguous elements
// each (float4 loads). Local register scan + single 6-step shuffle scan of
// (A,B) lane summaries per direction; fused 4-way max + float4 store.
constexpr int WSEG = 16;
constexpr int NLANE = Wn / WSEG;     // 40 active lanes

template <bool HAS_UP>
__global__ __launch_bounds__(512) void horiz(
    const float* __restrict__ x, const float* __restrict__ g2,
    const float* __restrict__ g3, const float* __restrict__ down,
    const float* __restrict__ up, float* __restrict__ out) {
  int wv = threadIdx.x >> 6;
  int l = threadIdx.x & 63;
  int row = blockIdx.x * 8 + wv;
  bool act = l < NLANE;
  size_t base = (size_t)row * Wn + (size_t)l * WSEG;

  float xv[WSEG], gv[WSEG], rr[WSEG], rl[WSEG], P[WSEG];

  if (act) {
#pragma unroll
    for (int q = 0; q < WSEG / 4; ++q) {
      float4 t = ((const float4*)(x + base))[q];
      xv[4 * q] = t.x; xv[4 * q + 1] = t.y; xv[4 * q + 2] = t.z; xv[4 * q + 3] = t.w;
      float4 u = ((const float4*)(g2 + base))[q];
      gv[4 * q] = u.x; gv[4 * q + 1] = u.y; gv[4 * q + 2] = u.z; gv[4 * q + 3] = u.w;
    }
  }

  // ---- forward (r_right) ----
  float yy = 0.0f, pp = 1.0f;
#pragma unroll
  for (int i = 0; i < WSEG; ++i) {
    float b = (l == 0 && i == 0) ? 0.0f : gv[i];
    yy = fmaf(b, yy - xv[i], xv[i]);
    pp *= b;
    rr[i] = yy;
    P[i] = pp;
  }
  float A = act ? yy : 0.0f;
  float B = act ? pp : 1.0f;
#pragma unroll
  for (int off = 1; off < 64; off <<= 1) {
    float Au = __shfl_up(A, off);
    float Bu = __shfl_up(B, off);
    if (l >= off) { A = fmaf(B, Au, A); B *= Bu; }
  }
  float c = __shfl_up(A, 1);
  if (l == 0) c = 0.0f;
#pragma unroll
  for (int i = 0; i < WSEG; ++i) rr[i] = fmaf(P[i], c, rr[i]);

  // ---- backward (r_left) ----
  if (act) {
#pragma unroll
    for (int q = 0; q < WSEG / 4; ++q) {
      float4 u = ((const float4*)(g3 + base))[q];
      gv[4 * q] = u.x; gv[4 * q + 1] = u.y; gv[4 * q + 2] = u.z; gv[4 * q + 3] = u.w;
    }
  }
  yy = 0.0f; pp = 1.0f;
#pragma unroll
  for (int i = WSEG - 1; i >= 0; --i) {
    float b = (l == NLANE - 1 && i == WSEG - 1) ? 0.0f : gv[i];
    yy = fmaf(b, yy - xv[i], xv[i]);
    pp *= b;
    rl[i] = yy;
    P[i] = pp;
  }
  A = act ? yy : 0.0f;   // inactive lanes: identity (A=0,B=1) so shfl_down is safe
  B = act ? pp : 1.0f;
#pragma unroll
  for (int off = 1; off < 64; off <<= 1) {
    float Ad = __shfl_down(A, off);
    float Bd = __shfl_down(B, off);
    if (l + off < 64) { A = fmaf(B, Ad, A); B *= Bd; }
  }
  float c2 = __shfl_down(A, 1);
  if (l >= NLANE - 1) c2 = 0.0f;
#pragma unroll
  for (int i = 0; i < WSEG; ++i) rl[i] = fmaf(P[i], c2, rl[i]);

  // ---- fused 4-way max + store ----
  if (act) {
#pragma unroll
    for (int q = 0; q < WSEG / 4; ++q) {
      float4 dn = ((const float4*)(down + base))[q];
      float4 uv;
      if (HAS_UP) uv = ((const float4*)(up + base))[q];
      float4 o;
      o.x = fmaxf(fmaxf(dn.x, rr[4 * q + 0]), rl[4 * q + 0]);
      o.y = fmaxf(fmaxf(dn.y, rr[4 * q + 1]), rl[4 * q + 1]);
      o.z = fmaxf(fmaxf(dn.z, rr[4 * q + 2]), rl[4 * q + 2]);
      o.w = fmaxf(fmaxf(dn.w, rr[4 * q + 3]), rl[4 * q + 3]);
      if (HAS_UP) {
        o.x = fmaxf(o.x, uv.x);
        o.y = fmaxf(o.y, uv.y);
        o.z = fmaxf(o.z, uv.z);
        o.w = fmaxf(o.w, uv.w);
      }
      ((float4*)(out + base))[q] = o;
    }
  }
}

extern "C" void kernel_launch(void* const* d_in, const int* in_sizes, int n_in,
                              void* d_out, int out_size, void* d_ws,
                              size_t ws_size, hipStream_t stream) {
  const float* x = (const float*)d_in[0];
  const float* g0 = (const float*)d_in[1];
  const float* g1 = (const float*)d_in[2];
  const float* g2 = (const float*)d_in[3];
  const float* g3 = (const float*)d_in[4];
  float* out = (float*)d_out;

  size_t need = (size_t)out_size * sizeof(float);
  if (ws_size >= need) {
    float* ws = (float*)d_ws;
    // fwd half writes r_down -> out, bwd half writes r_up -> ws
    vert<<<2 * (NCOL / 64), VBLK, 0, stream>>>(x, g0, g1, out, ws);
    horiz<true><<<NROW / 8, 512, 0, stream>>>(x, g2, g3, out, ws, out);
  } else {
    vert_fused<<<NCOL / 256, 256, 0, stream>>>(x, g0, g1, out);
    horiz<false><<<NROW / 8, 512, 0, stream>>>(x, g2, g3, out, nullptr, out);
  }
}